// Round 4
// baseline (201.545 us; speedup 1.0000x reference)
//
#include <hip/hip_runtime.h>
#include <hip/hip_bf16.h>

// Problem constants (B=2, T=2048, D=1024, H=16, hd=64)
#define T_SEQ 2048
#define DM    1024
#define MTOT  4096   // B*T

typedef short v8s __attribute__((ext_vector_type(8)));   // 8 x bf16 (4 VGPRs)
typedef float v4f __attribute__((ext_vector_type(4)));   // MFMA accumulator

// fp32 -> bf16 round-to-nearest-even
__device__ __forceinline__ unsigned short f2bf(float f) {
  union { float f; unsigned int u; } x; x.f = f;
  return (unsigned short)((x.u + (((x.u >> 16) & 1u) + 0x7fffu)) >> 16);
}

// async global->LDS, 16B per lane: lane i lands at lds + i*16 (wave-uniform base).
__device__ __forceinline__ void gload16(const void* g, void* lds) {
  __builtin_amdgcn_global_load_lds(
      (const __attribute__((address_space(1))) unsigned int*)g,
      (__attribute__((address_space(3))) unsigned int*)lds, 16, 0, 0);
}

// ---------------------------------------------------------------------------
// Convert x + Wq/Wk/Wv/Wo to bf16 in workspace.
// ---------------------------------------------------------------------------
__global__ __launch_bounds__(256) void convert_all(
    const float* __restrict__ x,
    const float* __restrict__ Wq, const float* __restrict__ Wk,
    const float* __restrict__ Wv, const float* __restrict__ Wo,
    unsigned short* __restrict__ xb, unsigned short* __restrict__ wb)
{
  int i = blockIdx.x * 256 + threadIdx.x;   // float4 index, 2^21 total
  const float4* src;
  ushort4* dst;
  int idx;
  if (i < (1 << 20)) {
    src = (const float4*)x; dst = (ushort4*)xb; idx = i;
  } else {
    int j = i - (1 << 20);
    int wsel = j >> 18;
    idx = j & ((1 << 18) - 1);
    const float* s = (wsel == 0) ? Wq : (wsel == 1) ? Wk : (wsel == 2) ? Wv : Wo;
    src = (const float4*)s;
    dst = (ushort4*)(wb + (size_t)wsel * DM * DM);
  }
  float4 v = src[idx];
  ushort4 o = { f2bf(v.x), f2bf(v.y), f2bf(v.z), f2bf(v.w) };
  dst[idx] = o;
}

// ---------------------------------------------------------------------------
// FUSED QKV: one block computes the 128x128 tile of Q, K and V for the same
// A-tile (x). A staged ONCE per K-step + 3 W-tiles -> 96 MFMA per barrier
// pair. Grid 32x8 = 256 blocks = exactly 1/CU, one round.
// LDS: As 16KB | Wq 16KB | Wk 16KB | Wv 16KB = 64KB. XOR chunk swizzle.
// z=2 (V) epilogue: LDS transpose -> panel layout
//   Vt[((bh*16 + tblk)*64 + d)*128 + (t&127)].
// ---------------------------------------------------------------------------
__global__ __launch_bounds__(256) void qkv_fused(
    const unsigned short* __restrict__ xb,
    const unsigned short* __restrict__ wb,
    unsigned short* __restrict__ Qw, unsigned short* __restrict__ Kw,
    unsigned short* __restrict__ Vtw)
{
  __shared__ unsigned short smem[4 * 128 * 64];   // 64KB
  unsigned short* As = smem;

  const int tid  = threadIdx.x;
  const int wv   = tid >> 6, l = tid & 63;
  const int lrow = l & 15, lq = l >> 4;
  const int wm = wv >> 1, wn = wv & 1;
  const int srow = l >> 3, sslot = l & 7;
  const int swz  = sslot ^ (srow & 7);
  const int m0 = blockIdx.x * 128, n0 = blockIdx.y * 128;

  v4f acc[3][4][4];
#pragma unroll
  for (int z = 0; z < 3; ++z)
#pragma unroll
    for (int mt = 0; mt < 4; ++mt)
#pragma unroll
      for (int nt = 0; nt < 4; ++nt) acc[z][mt][nt] = (v4f){0.f, 0.f, 0.f, 0.f};

  const size_t aBase = (size_t)(m0 + wv * 8 + srow) * DM + swz * 8;
  const size_t bBase = (size_t)(n0 + wv * 8 + srow) * DM + swz * 8;

  for (int k0 = 0; k0 < DM; k0 += 64) {
    __syncthreads();
#pragma unroll
    for (int i = 0; i < 4; ++i)
      gload16(xb + aBase + (size_t)i * 32 * DM + k0, As + i * 2048 + wv * 512);
#pragma unroll
    for (int z = 0; z < 3; ++z)
#pragma unroll
      for (int i = 0; i < 4; ++i)
        gload16(wb + (size_t)z * DM * DM + bBase + (size_t)i * 32 * DM + k0,
                smem + (1 + z) * 8192 + i * 2048 + wv * 512);
    __syncthreads();
#pragma unroll
    for (int kc = 0; kc < 2; ++kc) {
      const int aslot = ((kc << 2) | lq) ^ (lrow & 7);
      v8s af[4];
#pragma unroll
      for (int mt = 0; mt < 4; ++mt)
        af[mt] = *(const v8s*)&As[(wm * 64 + mt * 16 + lrow) * 64 + aslot * 8];
#pragma unroll
      for (int z = 0; z < 3; ++z) {
        const unsigned short* Bz = smem + (1 + z) * 8192;
        v8s bf[4];
#pragma unroll
        for (int nt = 0; nt < 4; ++nt)
          bf[nt] = *(const v8s*)&Bz[(wn * 64 + nt * 16 + lrow) * 64 + aslot * 8];
#pragma unroll
        for (int mt = 0; mt < 4; ++mt)
#pragma unroll
          for (int nt = 0; nt < 4; ++nt)
            acc[z][mt][nt] = __builtin_amdgcn_mfma_f32_16x16x32_bf16(
                af[mt], bf[nt], acc[z][mt][nt], 0, 0, 0);
      }
    }
  }

  // Q and K: direct row-major stores (no LDS needed)
#pragma unroll
  for (int z = 0; z < 2; ++z) {
    unsigned short* Y = z ? Kw : Qw;
#pragma unroll
    for (int mt = 0; mt < 4; ++mt)
#pragma unroll
      for (int nt = 0; nt < 4; ++nt)
#pragma unroll
        for (int r = 0; r < 4; ++r) {
          int row = m0 + wm * 64 + mt * 16 + lq * 4 + r;
          int col = n0 + wn * 64 + nt * 16 + lrow;
          Y[(size_t)row * DM + col] = f2bf(acc[z][mt][nt][r]);
        }
  }

  // V: stage C-tile into swizzled LDS (first 32KB of smem), then b128 panel
  __syncthreads();   // K-loop LDS reads done
#pragma unroll
  for (int mt = 0; mt < 4; ++mt)
#pragma unroll
    for (int nt = 0; nt < 4; ++nt)
#pragma unroll
      for (int r = 0; r < 4; ++r) {
        int trow = wm * 64 + mt * 16 + lq * 4 + r;
        int col  = wn * 64 + nt * 16 + lrow;
        int ch = col >> 3;
        int slot = (ch & 8) | ((ch & 7) ^ (trow & 7));
        smem[trow * 128 + slot * 8 + (col & 7)] = f2bf(acc[2][mt][nt][r]);
      }
  __syncthreads();
  {
    const int d128 = tid & 127;
    const int halfsel = tid >> 7;
    const int bb = m0 >> 11;
    const int tblk = (m0 & 2047) >> 7;
    const int bh = bb * 16 + ((n0 + d128) >> 6);
    const int dh = d128 & 63;
    unsigned short* dst = Vtw + (((size_t)bh * 16 + tblk) * 64 + dh) * 128;
    const int ch = d128 >> 3, e7 = d128 & 7;
#pragma unroll
    for (int j = 0; j < 8; ++j) {
      int tchunk = j * 2 + halfsel;
      unsigned short vals[8];
#pragma unroll
      for (int e = 0; e < 8; ++e) {
        int tr = tchunk * 8 + e;
        int slot = (ch & 8) | ((ch & 7) ^ (tr & 7));
        vals[e] = smem[tr * 128 + slot * 8 + e7];
      }
      *(v8s*)(dst + tchunk * 8) = *(const v8s*)vals;
    }
  }
}

// ---------------------------------------------------------------------------
// 128x128 GEMM (oproj): Y = AO @ Wo^T, fp32 out.
// ---------------------------------------------------------------------------
__global__ __launch_bounds__(256) void oproj_gemm128(
    const unsigned short* __restrict__ AO,
    const unsigned short* __restrict__ Wob,
    float* __restrict__ Y)
{
  __shared__ unsigned short smem[2 * 128 * 64];
  unsigned short* As = smem;
  unsigned short* Bs = smem + 8192;
  const int tid  = threadIdx.x;
  const int wv   = tid >> 6, l = tid & 63;
  const int lrow = l & 15, lq = l >> 4;
  const int wm = wv >> 1, wn = wv & 1;
  const int srow = l >> 3, sslot = l & 7;
  const int swz  = sslot ^ (srow & 7);
  const int m0 = blockIdx.x * 128, n0 = blockIdx.y * 128;

  v4f acc[4][4];
#pragma unroll
  for (int mt = 0; mt < 4; ++mt)
#pragma unroll
    for (int nt = 0; nt < 4; ++nt) acc[mt][nt] = (v4f){0.f, 0.f, 0.f, 0.f};

  const size_t aBase = (size_t)(m0 + wv * 8 + srow) * DM + swz * 8;
  const size_t bBase = (size_t)(n0 + wv * 8 + srow) * DM + swz * 8;

  for (int k0 = 0; k0 < DM; k0 += 64) {
    __syncthreads();
#pragma unroll
    for (int i = 0; i < 4; ++i) {
      gload16(AO  + aBase + (size_t)i * 32 * DM + k0, As + i * 2048 + wv * 512);
      gload16(Wob + bBase + (size_t)i * 32 * DM + k0, Bs + i * 2048 + wv * 512);
    }
    __syncthreads();
#pragma unroll
    for (int kc = 0; kc < 2; ++kc) {
      const int aslot = ((kc << 2) | lq) ^ (lrow & 7);
      v8s af[4], bf[4];
#pragma unroll
      for (int mt = 0; mt < 4; ++mt)
        af[mt] = *(const v8s*)&As[(wm * 64 + mt * 16 + lrow) * 64 + aslot * 8];
#pragma unroll
      for (int nt = 0; nt < 4; ++nt)
        bf[nt] = *(const v8s*)&Bs[(wn * 64 + nt * 16 + lrow) * 64 + aslot * 8];
#pragma unroll
      for (int mt = 0; mt < 4; ++mt)
#pragma unroll
        for (int nt = 0; nt < 4; ++nt)
          acc[mt][nt] = __builtin_amdgcn_mfma_f32_16x16x32_bf16(
              af[mt], bf[nt], acc[mt][nt], 0, 0, 0);
    }
  }
#pragma unroll
  for (int mt = 0; mt < 4; ++mt)
#pragma unroll
    for (int nt = 0; nt < 4; ++nt)
#pragma unroll
      for (int r = 0; r < 4; ++r) {
        int row = m0 + wm * 64 + mt * 16 + lq * 4 + r;
        int col = n0 + wn * 64 + nt * 16 + lrow;
        Y[(size_t)row * DM + col] = acc[mt][nt][r];
      }
}

// ---------------------------------------------------------------------------
// Flash attention, Q-tile 128 (wave owns 32 q-rows), KT=128, fixed-base
// softmax. Per iter: 32KB staged, 64 MFMA/wave. Grid 512 = 2 blocks/CU,
// all resident; qt pairing (15 with 0, 14 with 1, ...) balances CUs.
// ---------------------------------------------------------------------------
__global__ __launch_bounds__(256) void attn4(
    const unsigned short* __restrict__ Q,
    const unsigned short* __restrict__ K,
    const unsigned short* __restrict__ Vt,
    unsigned short* __restrict__ O)
{
  __shared__ unsigned short Ks[128 * 64];    // 16KB [key][chunk swz]
  __shared__ unsigned short Vts[64 * 128];   // 16KB [d][chunk swz]
  __shared__ unsigned short Ps[128 * 128];   // 32KB [qrow][chunk swz]

  const int tid  = threadIdx.x;
  const int wave = tid >> 6;
  const int lane = tid & 63;
  const int lrow = lane & 15;
  const int lq   = lane >> 4;
  const int gid  = blockIdx.x;
  // first 256 blocks: qt 15..8 ; second 256: qt 0..7  -> CU pairs sum to 17
  const int qt   = (gid < 256) ? (15 - (gid >> 5)) : ((gid >> 5) - 8);
  const int bh   = gid & 31;
  const int b = bh >> 4, h = bh & 15;

  // Q fragments: wave owns rows wave*32 + mt*16 + lrow
  v8s qf[2][2];
#pragma unroll
  for (int mt = 0; mt < 2; ++mt) {
    const unsigned short* qp =
        Q + ((size_t)(b * T_SEQ + qt * 128 + wave * 32 + mt * 16 + lrow)) * DM + h * 64;
    qf[mt][0] = *(const v8s*)(qp + lq * 8);
    qf[mt][1] = *(const v8s*)(qp + 32 + lq * 8);
  }

  v4f oacc[2][4];
#pragma unroll
  for (int mt = 0; mt < 2; ++mt)
#pragma unroll
    for (int nt = 0; nt < 4; ++nt) oacc[mt][nt] = (v4f){0.f, 0.f, 0.f, 0.f};
  float psum[2][4] = {{0.f,0.f,0.f,0.f},{0.f,0.f,0.f,0.f}};

  const int nkt = qt + 1;

  const int kchunk = (lane & 7) ^ ((lane >> 3) & 7);
  const unsigned short* kg =
      K + ((size_t)(b * T_SEQ) + wave * 8 + (lane >> 3)) * DM + h * 64 + kchunk * 8;
  unsigned short* kdst = Ks + (wave * 8) * 64;
  const int vd = wave * 4 + (lane >> 4);
  const int vslot = lane & 15;
  const int vchunk = (vslot & 8) | ((vslot & 7) ^ (vd & 7));
  const unsigned short* vg =
      Vt + ((size_t)bh * 1024 + vd) * 128 + vchunk * 8;
  unsigned short* vdst = Vts + (wave * 4) * 128;

  for (int kt = 0; kt < nkt; ++kt) {
    __syncthreads();
#pragma unroll
    for (int i = 0; i < 4; ++i)
      gload16(kg + ((size_t)kt * 128 + i * 32) * DM, kdst + i * 32 * 64);
#pragma unroll
    for (int i = 0; i < 4; ++i)
      gload16(vg + (size_t)kt * 8192 + i * 2048, vdst + i * 16 * 128);
    __syncthreads();

    // S = Q K^T : 32 q-rows x 128 keys per wave
    v4f s[2][8];
#pragma unroll
    for (int mt = 0; mt < 2; ++mt)
#pragma unroll
      for (int nt = 0; nt < 8; ++nt) {
        v4f a = {0.f, 0.f, 0.f, 0.f};
#pragma unroll
        for (int kc = 0; kc < 2; ++kc) {
          int slot = (kc * 4 + lq) ^ (lrow & 7);
          v8s bfr = *(const v8s*)&Ks[(nt * 16 + lrow) * 64 + slot * 8];
          a = __builtin_amdgcn_mfma_f32_16x16x32_bf16(qf[mt][kc], bfr, a, 0, 0, 0);
        }
        s[mt][nt] = a;
      }

    // p = exp2(s/8*log2e - 16*log2e); mask on diagonal tile; stash bf16
    const bool last = (kt == qt);
#pragma unroll
    for (int mt = 0; mt < 2; ++mt)
#pragma unroll
      for (int nt = 0; nt < 8; ++nt)
#pragma unroll
        for (int r = 0; r < 4; ++r) {
          float p = exp2f(fmaf(s[mt][nt][r], 0.18033688f, -23.0831206f));
          if (last && (nt * 16 + lrow > wave * 32 + mt * 16 + lq * 4 + r)) p = 0.f;
          psum[mt][r] += p;
          unsigned int bits = __float_as_uint(p);
          int row = wave * 32 + mt * 16 + lq * 4 + r;
          int ch = nt * 2 + (lrow >> 3);
          int slot = (ch & 8) | ((ch & 7) ^ (row & 7));
          Ps[row * 128 + slot * 8 + (lrow & 7)] =
              (unsigned short)((bits + 0x8000u) >> 16);
        }

    // P frags (wave-private rows) + O += P @ V
#pragma unroll
    for (int mt = 0; mt < 2; ++mt) {
      v8s pf[4];
#pragma unroll
      for (int kc = 0; kc < 4; ++kc) {
        int ch = kc * 4 + lq;
        int slot = (ch & 8) | ((ch & 7) ^ (lrow & 7));
        pf[kc] = *(const v8s*)&Ps[(wave * 32 + mt * 16 + lrow) * 128 + slot * 8];
      }
#pragma unroll
      for (int nt = 0; nt < 4; ++nt)
#pragma unroll
        for (int kc = 0; kc < 4; ++kc) {
          int ch = kc * 4 + lq;
          int slot = (ch & 8) | ((ch & 7) ^ (lrow & 7));
          v8s vb = *(const v8s*)&Vts[(nt * 16 + lrow) * 128 + slot * 8];
          oacc[mt][nt] = __builtin_amdgcn_mfma_f32_16x16x32_bf16(
              pf[kc], vb, oacc[mt][nt], 0, 0, 0);
        }
    }
  }

  // final row-sum reduction (16 lanes share a q-row) + O write
#pragma unroll
  for (int mt = 0; mt < 2; ++mt)
#pragma unroll
    for (int r = 0; r < 4; ++r) {
      float ps = psum[mt][r];
#pragma unroll
      for (int off = 1; off < 16; off <<= 1) ps += __shfl_xor(ps, off);
      psum[mt][r] = ps;
    }
#pragma unroll
  for (int mt = 0; mt < 2; ++mt)
#pragma unroll
    for (int nt = 0; nt < 4; ++nt)
#pragma unroll
      for (int r = 0; r < 4; ++r) {
        int trow = qt * 128 + wave * 32 + mt * 16 + lq * 4 + r;
        int col  = h * 64 + nt * 16 + lrow;
        O[((size_t)(b * T_SEQ + trow)) * DM + col] = f2bf(oacc[mt][nt][r] / psum[mt][r]);
      }
}

// ---------------------------------------------------------------------------
extern "C" void kernel_launch(void* const* d_in, const int* in_sizes, int n_in,
                              void* d_out, int out_size, void* d_ws, size_t ws_size,
                              hipStream_t stream) {
  const float* x  = (const float*)d_in[0];
  const float* Wq = (const float*)d_in[1];
  const float* Wk = (const float*)d_in[2];
  const float* Wv = (const float*)d_in[3];
  const float* Wo = (const float*)d_in[4];
  float* out = (float*)d_out;

  unsigned short* xb  = (unsigned short*)d_ws;
  unsigned short* wb  = xb + (size_t)MTOT * DM;
  unsigned short* Qw  = wb + (size_t)4 * DM * DM;
  unsigned short* Kw  = Qw + (size_t)MTOT * DM;
  unsigned short* Vtw = Kw + (size_t)MTOT * DM;
  unsigned short* AO  = xb;   // xb dead after qkv_fused -> reuse

  convert_all<<<8192, 256, 0, stream>>>(x, Wq, Wk, Wv, Wo, xb, wb);
  qkv_fused<<<dim3(32, 8), 256, 0, stream>>>(xb, wb, Qw, Kw, Vtw);
  attn4<<<512, 256, 0, stream>>>(Qw, Kw, Vtw, AO);
  oproj_gemm128<<<dim3(32, 8), 256, 0, stream>>>(AO, wb + (size_t)3 * DM * DM, out);
}

// Round 5
// 172.559 us; speedup vs baseline: 1.1680x; 1.1680x over previous
//
#include <hip/hip_runtime.h>
#include <hip/hip_bf16.h>

// Problem constants (B=2, T=2048, D=1024, H=16, hd=64)
#define T_SEQ 2048
#define DM    1024
#define MTOT  4096   // B*T

typedef short v8s __attribute__((ext_vector_type(8)));   // 8 x bf16 (4 VGPRs)
typedef float v4f __attribute__((ext_vector_type(4)));   // MFMA accumulator

// fp32 -> bf16 round-to-nearest-even
__device__ __forceinline__ unsigned short f2bf(float f) {
  union { float f; unsigned int u; } x; x.f = f;
  return (unsigned short)((x.u + (((x.u >> 16) & 1u) + 0x7fffu)) >> 16);
}

// async global->LDS, 16B per lane: lane i lands at lds + i*16 (wave-uniform base).
__device__ __forceinline__ void gload16(const void* g, void* lds) {
  __builtin_amdgcn_global_load_lds(
      (const __attribute__((address_space(1))) unsigned int*)g,
      (__attribute__((address_space(3))) unsigned int*)lds, 16, 0, 0);
}

// ---------------------------------------------------------------------------
// Convert x + Wq/Wk/Wv/Wo to bf16 in workspace.
// ---------------------------------------------------------------------------
__global__ __launch_bounds__(256) void convert_all(
    const float* __restrict__ x,
    const float* __restrict__ Wq, const float* __restrict__ Wk,
    const float* __restrict__ Wv, const float* __restrict__ Wo,
    unsigned short* __restrict__ xb, unsigned short* __restrict__ wb)
{
  int i = blockIdx.x * 256 + threadIdx.x;   // float4 index, 2^21 total
  const float4* src;
  ushort4* dst;
  int idx;
  if (i < (1 << 20)) {
    src = (const float4*)x; dst = (ushort4*)xb; idx = i;
  } else {
    int j = i - (1 << 20);
    int wsel = j >> 18;
    idx = j & ((1 << 18) - 1);
    const float* s = (wsel == 0) ? Wq : (wsel == 1) ? Wk : (wsel == 2) ? Wv : Wo;
    src = (const float4*)s;
    dst = (ushort4*)(wb + (size_t)wsel * DM * DM);
  }
  float4 v = src[idx];
  ushort4 o = { f2bf(v.x), f2bf(v.y), f2bf(v.z), f2bf(v.w) };
  dst[idx] = o;
}

// ---------------------------------------------------------------------------
// FUSED QKV v2: tile 128M x 64N, grid (32,16) = 512 blocks = 2/CU (one round,
// 2-way co-residency). A staged ONCE per K-step + 3 64-row W tiles.
// LDS: As 16KB | Wq 8KB | Wk 8KB | Wv 8KB = 40KB. XOR chunk swizzle (slot s
// of row r holds k-chunk s^(r&7)) -> conflict-free b128 reads.
// Per barrier pair: 48 MFMA/wave. N=64 => V epilogue covers exactly one head:
// contiguous panel Vt[((bh*16+tblk)*64 + d)*128 + t].
// ---------------------------------------------------------------------------
__global__ __launch_bounds__(256) void qkv_fused2(
    const unsigned short* __restrict__ xb,
    const unsigned short* __restrict__ wb,
    unsigned short* __restrict__ Qw, unsigned short* __restrict__ Kw,
    unsigned short* __restrict__ Vtw)
{
  __shared__ unsigned short smem[20480];   // 40KB
  unsigned short* As = smem;               // [128][64]

  const int tid  = threadIdx.x;
  const int wv   = tid >> 6, l = tid & 63;
  const int lrow = l & 15, lq = l >> 4;
  const int wm = wv >> 1;        // m-half (64 rows)
  const int wn = wv & 1;         // n-half (32 cols)
  const int srow = l >> 3, sslot = l & 7;
  const int swz  = sslot ^ (srow & 7);
  const int m0 = blockIdx.x * 128, n0 = blockIdx.y * 64;

  v4f acc[3][4][2];
#pragma unroll
  for (int z = 0; z < 3; ++z)
#pragma unroll
    for (int mt = 0; mt < 4; ++mt)
#pragma unroll
      for (int nt = 0; nt < 2; ++nt) acc[z][mt][nt] = (v4f){0.f, 0.f, 0.f, 0.f};

  // A: 16 row-chunks of 8; wave stages 4 (rows [32wv, 32wv+32)).
  const size_t aBase = (size_t)(m0 + wv * 32 + srow) * DM + swz * 8;
  // W: 8 row-chunks per z; wave stages 2 per z (rows [16wv, 16wv+16)).
  const size_t bBase = (size_t)(n0 + wv * 16 + srow) * DM + swz * 8;

  for (int k0 = 0; k0 < DM; k0 += 64) {
    __syncthreads();
#pragma unroll
    for (int i = 0; i < 4; ++i)
      gload16(xb + aBase + (size_t)i * 8 * DM + k0, As + (wv * 32 + i * 8) * 64);
#pragma unroll
    for (int z = 0; z < 3; ++z)
#pragma unroll
      for (int i = 0; i < 2; ++i)
        gload16(wb + (size_t)z * DM * DM + bBase + (size_t)i * 8 * DM + k0,
                smem + 8192 + z * 4096 + (wv * 16 + i * 8) * 64);
    __syncthreads();
#pragma unroll
    for (int kc = 0; kc < 2; ++kc) {
      const int aslot = ((kc << 2) | lq) ^ (lrow & 7);
      v8s af[4];
#pragma unroll
      for (int mt = 0; mt < 4; ++mt)
        af[mt] = *(const v8s*)&As[(wm * 64 + mt * 16 + lrow) * 64 + aslot * 8];
#pragma unroll
      for (int z = 0; z < 3; ++z) {
        const unsigned short* Bz = smem + 8192 + z * 4096;
        v8s bf[2];
#pragma unroll
        for (int nt = 0; nt < 2; ++nt)
          bf[nt] = *(const v8s*)&Bz[(wn * 32 + nt * 16 + lrow) * 64 + aslot * 8];
#pragma unroll
        for (int mt = 0; mt < 4; ++mt)
#pragma unroll
          for (int nt = 0; nt < 2; ++nt)
            acc[z][mt][nt] = __builtin_amdgcn_mfma_f32_16x16x32_bf16(
                af[mt], bf[nt], acc[z][mt][nt], 0, 0, 0);
      }
    }
  }

  // Q and K: direct row-major stores
#pragma unroll
  for (int z = 0; z < 2; ++z) {
    unsigned short* Y = z ? Kw : Qw;
#pragma unroll
    for (int mt = 0; mt < 4; ++mt)
#pragma unroll
      for (int nt = 0; nt < 2; ++nt)
#pragma unroll
        for (int r = 0; r < 4; ++r) {
          int row = m0 + wm * 64 + mt * 16 + lq * 4 + r;
          int col = n0 + wn * 32 + nt * 16 + lrow;
          Y[(size_t)row * DM + col] = f2bf(acc[z][mt][nt][r]);
        }
  }

  // V: stage C-tile [128 t][64 d] swizzled in LDS, then b128 panel writes
  __syncthreads();   // K-loop LDS reads done
#pragma unroll
  for (int mt = 0; mt < 4; ++mt)
#pragma unroll
    for (int nt = 0; nt < 2; ++nt)
#pragma unroll
      for (int r = 0; r < 4; ++r) {
        int trow = wm * 64 + mt * 16 + lq * 4 + r;     // 0..127 (token)
        int col  = wn * 32 + nt * 16 + lrow;           // 0..63  (d)
        int slot = (col >> 3) ^ (trow & 7);
        smem[trow * 64 + slot * 8 + (col & 7)] = f2bf(acc[2][mt][nt][r]);
      }
  __syncthreads();
  {
    const int d = tid & 63;
    const int quarter = tid >> 6;        // 4 t-chunks of 32
    const int b = m0 >> 11;
    const int tblk = (m0 & 2047) >> 7;
    const int h = n0 >> 6;
    const int bh = b * 16 + h;
    unsigned short* dst = Vtw + (((size_t)bh * 16 + tblk) * 64 + d) * 128;
    const int ch = d >> 3, e7 = d & 7;
#pragma unroll
    for (int j = 0; j < 4; ++j) {
      int tbase = quarter * 32 + j * 8;
      unsigned short vals[8];
#pragma unroll
      for (int e = 0; e < 8; ++e)
        vals[e] = smem[(tbase + e) * 64 + (ch ^ e) * 8 + e7];
      *(v8s*)(dst + tbase) = *(const v8s*)vals;
    }
  }
}

// ---------------------------------------------------------------------------
// Output projection v2: tile 64M x 128N, grid (64,8) = 512 = 2/CU.
// LDS: As 8KB + Bs 16KB = 24KB. Same swizzle scheme. fp32 out.
// ---------------------------------------------------------------------------
__global__ __launch_bounds__(256) void oproj_gemm2(
    const unsigned short* __restrict__ AO,
    const unsigned short* __restrict__ Wob,
    float* __restrict__ Y)
{
  __shared__ unsigned short smem[12288];   // 24KB
  unsigned short* As = smem;               // [64][64]
  unsigned short* Bs = smem + 4096;        // [128][64]

  const int tid  = threadIdx.x;
  const int wv   = tid >> 6, l = tid & 63;
  const int lrow = l & 15, lq = l >> 4;
  const int wm = wv >> 1;        // m-half (32 rows)
  const int wn = wv & 1;         // n-half (64 cols)
  const int srow = l >> 3, sslot = l & 7;
  const int swz  = sslot ^ (srow & 7);
  const int m0 = blockIdx.x * 64, n0 = blockIdx.y * 128;

  v4f acc[2][4];
#pragma unroll
  for (int mt = 0; mt < 2; ++mt)
#pragma unroll
    for (int nt = 0; nt < 4; ++nt) acc[mt][nt] = (v4f){0.f, 0.f, 0.f, 0.f};

  // A: 8 chunks; wave stages 2 (rows [16wv,16wv+16)). B: 16 chunks; wave stages 4.
  const size_t aBase = (size_t)(m0 + wv * 16 + srow) * DM + swz * 8;
  const size_t bBase = (size_t)(n0 + wv * 32 + srow) * DM + swz * 8;

  for (int k0 = 0; k0 < DM; k0 += 64) {
    __syncthreads();
#pragma unroll
    for (int i = 0; i < 2; ++i)
      gload16(AO + aBase + (size_t)i * 8 * DM + k0, As + (wv * 16 + i * 8) * 64);
#pragma unroll
    for (int i = 0; i < 4; ++i)
      gload16(Wob + bBase + (size_t)i * 8 * DM + k0, Bs + (wv * 32 + i * 8) * 64);
    __syncthreads();
#pragma unroll
    for (int kc = 0; kc < 2; ++kc) {
      const int aslot = ((kc << 2) | lq) ^ (lrow & 7);
      v8s af[2], bf[4];
#pragma unroll
      for (int mt = 0; mt < 2; ++mt)
        af[mt] = *(const v8s*)&As[(wm * 32 + mt * 16 + lrow) * 64 + aslot * 8];
#pragma unroll
      for (int nt = 0; nt < 4; ++nt)
        bf[nt] = *(const v8s*)&Bs[(wn * 64 + nt * 16 + lrow) * 64 + aslot * 8];
#pragma unroll
      for (int mt = 0; mt < 2; ++mt)
#pragma unroll
        for (int nt = 0; nt < 4; ++nt)
          acc[mt][nt] = __builtin_amdgcn_mfma_f32_16x16x32_bf16(
              af[mt], bf[nt], acc[mt][nt], 0, 0, 0);
    }
  }
#pragma unroll
  for (int mt = 0; mt < 2; ++mt)
#pragma unroll
    for (int nt = 0; nt < 4; ++nt)
#pragma unroll
      for (int r = 0; r < 4; ++r) {
        int row = m0 + wm * 32 + mt * 16 + lq * 4 + r;
        int col = n0 + wn * 64 + nt * 16 + lrow;
        Y[(size_t)row * DM + col] = acc[mt][nt][r];
      }
}

// ---------------------------------------------------------------------------
// Flash attention (R3-proven attn3): Q-tile 64, KT=128, fixed-base softmax
// (scores bounded; base cancels on normalization), gload16 staging, XOR
// swizzles, LPT grid order.
// ---------------------------------------------------------------------------
__global__ __launch_bounds__(256) void attn3(
    const unsigned short* __restrict__ Q,
    const unsigned short* __restrict__ K,
    const unsigned short* __restrict__ Vt,
    unsigned short* __restrict__ O)
{
  __shared__ unsigned short Ks[128 * 64];   // [key][chunk swz]  16KB
  __shared__ unsigned short Vts[64 * 128];  // [d][chunk swz]    16KB
  __shared__ unsigned short Ps[64 * 128];   // [qrow][chunk swz] 16KB

  const int tid  = threadIdx.x;
  const int wave = tid >> 6;
  const int lane = tid & 63;
  const int lrow = lane & 15;
  const int lq   = lane >> 4;
  const int gid  = blockIdx.x;
  const int qt   = 31 - (gid >> 5);   // LPT: longest first
  const int bh   = gid & 31;
  const int b = bh >> 4, h = bh & 15;

  const int qrow = qt * 64 + wave * 16 + lrow;
  const unsigned short* qp = Q + ((size_t)(b * T_SEQ + qrow)) * DM + h * 64;
  v8s qf[2] = { *(const v8s*)(qp + lq * 8), *(const v8s*)(qp + 32 + lq * 8) };

  v4f oacc[4];
#pragma unroll
  for (int nt = 0; nt < 4; ++nt) oacc[nt] = (v4f){0.f, 0.f, 0.f, 0.f};
  float psum[4] = {0.f, 0.f, 0.f, 0.f};

  const int nkt = (qt >> 1) + 1;

  const int kchunk = (lane & 7) ^ ((lane >> 3) & 7);
  const unsigned short* kg =
      K + ((size_t)(b * T_SEQ) + wave * 8 + (lane >> 3)) * DM + h * 64 + kchunk * 8;
  unsigned short* kdst = Ks + (wave * 8) * 64;
  const int vd = wave * 4 + (lane >> 4);
  const int vslot = lane & 15;
  const int vchunk = (vslot & 8) | ((vslot & 7) ^ (vd & 7));
  const unsigned short* vg =
      Vt + (((size_t)bh * 16) * 64 + vd) * 128 + vchunk * 8;
  unsigned short* vdst = Vts + (wave * 4) * 128;

  for (int kt = 0; kt < nkt; ++kt) {
    __syncthreads();
#pragma unroll
    for (int i = 0; i < 4; ++i)
      gload16(kg + ((size_t)kt * 128 + i * 32) * DM, kdst + i * 32 * 64);
#pragma unroll
    for (int i = 0; i < 4; ++i)
      gload16(vg + ((size_t)kt * 64 + i * 16) * 128, vdst + i * 16 * 128);
    __syncthreads();

    // S = Q K^T : 16 q-rows x 128 keys per wave
    v4f s[8];
#pragma unroll
    for (int nt = 0; nt < 8; ++nt) {
      v4f a = {0.f, 0.f, 0.f, 0.f};
#pragma unroll
      for (int kc = 0; kc < 2; ++kc) {
        int slot = (kc * 4 + lq) ^ (lrow & 7);
        v8s bfr = *(const v8s*)&Ks[(nt * 16 + lrow) * 64 + slot * 8];
        a = __builtin_amdgcn_mfma_f32_16x16x32_bf16(qf[kc], bfr, a, 0, 0, 0);
      }
      s[nt] = a;
    }

    // p = exp2(s*0.125*log2e - 16*log2e); mask; accumulate row-sum; stash bf16
    const bool last = (kt == nkt - 1);
    if (last) {
#pragma unroll
      for (int nt = 0; nt < 8; ++nt)
#pragma unroll
        for (int r = 0; r < 4; ++r) {
          float p = exp2f(fmaf(s[nt][r], 0.18033688f, -23.0831206f));
          if (kt * 128 + nt * 16 + lrow > qt * 64 + wave * 16 + lq * 4 + r) p = 0.f;
          psum[r] += p;
          unsigned int bits = __float_as_uint(p);
          int ch = nt * 2 + (lrow >> 3);
          int slot = (ch & 8) | ((ch & 7) ^ ((lq * 4 + r) & 7));
          Ps[(wave * 16 + lq * 4 + r) * 128 + slot * 8 + (lrow & 7)] =
              (unsigned short)((bits + 0x8000u) >> 16);
        }
    } else {
#pragma unroll
      for (int nt = 0; nt < 8; ++nt)
#pragma unroll
        for (int r = 0; r < 4; ++r) {
          float p = exp2f(fmaf(s[nt][r], 0.18033688f, -23.0831206f));
          psum[r] += p;
          unsigned int bits = __float_as_uint(p);
          int ch = nt * 2 + (lrow >> 3);
          int slot = (ch & 8) | ((ch & 7) ^ ((lq * 4 + r) & 7));
          Ps[(wave * 16 + lq * 4 + r) * 128 + slot * 8 + (lrow & 7)] =
              (unsigned short)((bits + 0x8000u) >> 16);
        }
    }

    // P frags (wave-private rows)
    v8s pf[4];
#pragma unroll
    for (int kc = 0; kc < 4; ++kc) {
      int ch = kc * 4 + lq;
      int slot = (ch & 8) | ((ch & 7) ^ (lrow & 7));
      pf[kc] = *(const v8s*)&Ps[(wave * 16 + lrow) * 128 + slot * 8];
    }

    // O += P @ V
#pragma unroll
    for (int nt = 0; nt < 4; ++nt)
#pragma unroll
      for (int kc = 0; kc < 4; ++kc) {
        int ch = kc * 4 + lq;
        int slot = (ch & 8) | ((ch & 7) ^ (lrow & 7));
        v8s vb = *(const v8s*)&Vts[(nt * 16 + lrow) * 128 + slot * 8];
        oacc[nt] = __builtin_amdgcn_mfma_f32_16x16x32_bf16(pf[kc], vb, oacc[nt], 0, 0, 0);
      }
  }

  // single final row-sum reduction (16 lanes share a q-row)
#pragma unroll
  for (int r = 0; r < 4; ++r) {
    float ps = psum[r];
#pragma unroll
    for (int off = 1; off < 16; off <<= 1) ps += __shfl_xor(ps, off);
    psum[r] = ps;
  }
#pragma unroll
  for (int nt = 0; nt < 4; ++nt)
#pragma unroll
    for (int r = 0; r < 4; ++r) {
      int trow = qt * 64 + wave * 16 + lq * 4 + r;
      int col  = h * 64 + nt * 16 + lrow;
      O[((size_t)(b * T_SEQ + trow)) * DM + col] = f2bf(oacc[nt][r] / psum[r]);
    }
}

// ---------------------------------------------------------------------------
extern "C" void kernel_launch(void* const* d_in, const int* in_sizes, int n_in,
                              void* d_out, int out_size, void* d_ws, size_t ws_size,
                              hipStream_t stream) {
  const float* x  = (const float*)d_in[0];
  const float* Wq = (const float*)d_in[1];
  const float* Wk = (const float*)d_in[2];
  const float* Wv = (const float*)d_in[3];
  const float* Wo = (const float*)d_in[4];
  float* out = (float*)d_out;

  unsigned short* xb  = (unsigned short*)d_ws;
  unsigned short* wb  = xb + (size_t)MTOT * DM;
  unsigned short* Qw  = wb + (size_t)4 * DM * DM;
  unsigned short* Kw  = Qw + (size_t)MTOT * DM;
  unsigned short* Vtw = Kw + (size_t)MTOT * DM;
  unsigned short* AO  = xb;   // xb dead after qkv_fused2 -> reuse

  convert_all<<<8192, 256, 0, stream>>>(x, Wq, Wk, Wv, Wo, xb, wb);
  qkv_fused2<<<dim3(32, 16), 256, 0, stream>>>(xb, wb, Qw, Kw, Vtw);
  attn3<<<1024, 256, 0, stream>>>(Qw, Kw, Vtw, AO);
  oproj_gemm2<<<dim3(64, 8), 256, 0, stream>>>(AO, wb + (size_t)3 * DM * DM, out);
}

// Round 7
// 169.687 us; speedup vs baseline: 1.1877x; 1.0169x over previous
//
#include <hip/hip_runtime.h>
#include <hip/hip_bf16.h>

// Problem constants (B=2, T=2048, D=1024, H=16, hd=64)
#define T_SEQ 2048
#define DM    1024
#define MTOT  4096   // B*T

typedef short v8s __attribute__((ext_vector_type(8)));   // 8 x bf16 (4 VGPRs)
typedef short v4s __attribute__((ext_vector_type(4)));   // 4 x bf16 (2 VGPRs)
typedef float v4f __attribute__((ext_vector_type(4)));   // MFMA accumulator

// fp32 -> bf16 round-to-nearest-even
__device__ __forceinline__ unsigned short f2bf(float f) {
  union { float f; unsigned int u; } x; x.f = f;
  return (unsigned short)((x.u + (((x.u >> 16) & 1u) + 0x7fffu)) >> 16);
}

// pack two v4f (P^T C-layout regs) -> one v8s B-operand for K=32 PV mfma
__device__ __forceinline__ v8s pack8bf(v4f a, v4f b) {
  union { v8s s; unsigned int u[4]; } o;
  o.u[0] = (unsigned int)f2bf(a[0]) | ((unsigned int)f2bf(a[1]) << 16);
  o.u[1] = (unsigned int)f2bf(a[2]) | ((unsigned int)f2bf(a[3]) << 16);
  o.u[2] = (unsigned int)f2bf(b[0]) | ((unsigned int)f2bf(b[1]) << 16);
  o.u[3] = (unsigned int)f2bf(b[2]) | ((unsigned int)f2bf(b[3]) << 16);
  return o.s;
}

// async global->LDS, 16B per lane: lane i lands at lds + i*16 (wave-uniform base).
__device__ __forceinline__ void gload16(const void* g, void* lds) {
  __builtin_amdgcn_global_load_lds(
      (const __attribute__((address_space(1))) unsigned int*)g,
      (__attribute__((address_space(3))) unsigned int*)lds, 16, 0, 0);
}

// ---------------------------------------------------------------------------
// Convert x + Wq/Wk/Wv/Wo to bf16 in workspace.
// ---------------------------------------------------------------------------
__global__ __launch_bounds__(256) void convert_all(
    const float* __restrict__ x,
    const float* __restrict__ Wq, const float* __restrict__ Wk,
    const float* __restrict__ Wv, const float* __restrict__ Wo,
    unsigned short* __restrict__ xb, unsigned short* __restrict__ wb)
{
  int i = blockIdx.x * 256 + threadIdx.x;   // float4 index, 2^21 total
  const float4* src;
  ushort4* dst;
  int idx;
  if (i < (1 << 20)) {
    src = (const float4*)x; dst = (ushort4*)xb; idx = i;
  } else {
    int j = i - (1 << 20);
    int wsel = j >> 18;
    idx = j & ((1 << 18) - 1);
    const float* s = (wsel == 0) ? Wq : (wsel == 1) ? Wk : (wsel == 2) ? Wv : Wo;
    src = (const float4*)s;
    dst = (ushort4*)(wb + (size_t)wsel * DM * DM);
  }
  float4 v = src[idx];
  ushort4 o = { f2bf(v.x), f2bf(v.y), f2bf(v.z), f2bf(v.w) };
  dst[idx] = o;
}

// ---------------------------------------------------------------------------
// FUSED QKV (R5-proven): tile 128M x 64N, grid (32,16) = 512 = 2/CU.
// LDS: As 16KB | Wq 8KB | Wk 8KB | Wv 8KB. XOR chunk swizzle.
// V epilogue: panel layout Vt[((bh*16+tblk)*64 + d)*128 + p] with PERMUTED
// key order: position p = P*32 + s*8 + h4*4 + j holds key t = P*32 + h4*16 +
// s*4 + j, so attn's b128 V^T reads match the P^T register layout exactly.
// ---------------------------------------------------------------------------
__global__ __launch_bounds__(256) void qkv_fused2(
    const unsigned short* __restrict__ xb,
    const unsigned short* __restrict__ wb,
    unsigned short* __restrict__ Qw, unsigned short* __restrict__ Kw,
    unsigned short* __restrict__ Vtw)
{
  __shared__ unsigned short smem[20480];   // 40KB
  unsigned short* As = smem;               // [128][64]

  const int tid  = threadIdx.x;
  const int wv   = tid >> 6, l = tid & 63;
  const int lrow = l & 15, lq = l >> 4;
  const int wm = wv >> 1;        // m-half (64 rows)
  const int wn = wv & 1;         // n-half (32 cols)
  const int srow = l >> 3, sslot = l & 7;
  const int swz  = sslot ^ (srow & 7);
  const int m0 = blockIdx.x * 128, n0 = blockIdx.y * 64;

  v4f acc[3][4][2];
#pragma unroll
  for (int z = 0; z < 3; ++z)
#pragma unroll
    for (int mt = 0; mt < 4; ++mt)
#pragma unroll
      for (int nt = 0; nt < 2; ++nt) acc[z][mt][nt] = (v4f){0.f, 0.f, 0.f, 0.f};

  const size_t aBase = (size_t)(m0 + wv * 32 + srow) * DM + swz * 8;
  const size_t bBase = (size_t)(n0 + wv * 16 + srow) * DM + swz * 8;

  for (int k0 = 0; k0 < DM; k0 += 64) {
    __syncthreads();
#pragma unroll
    for (int i = 0; i < 4; ++i)
      gload16(xb + aBase + (size_t)i * 8 * DM + k0, As + (wv * 32 + i * 8) * 64);
#pragma unroll
    for (int z = 0; z < 3; ++z)
#pragma unroll
      for (int i = 0; i < 2; ++i)
        gload16(wb + (size_t)z * DM * DM + bBase + (size_t)i * 8 * DM + k0,
                smem + 8192 + z * 4096 + (wv * 16 + i * 8) * 64);
    __syncthreads();
#pragma unroll
    for (int kc = 0; kc < 2; ++kc) {
      const int aslot = ((kc << 2) | lq) ^ (lrow & 7);
      v8s af[4];
#pragma unroll
      for (int mt = 0; mt < 4; ++mt)
        af[mt] = *(const v8s*)&As[(wm * 64 + mt * 16 + lrow) * 64 + aslot * 8];
#pragma unroll
      for (int z = 0; z < 3; ++z) {
        const unsigned short* Bz = smem + 8192 + z * 4096;
        v8s bf[2];
#pragma unroll
        for (int nt = 0; nt < 2; ++nt)
          bf[nt] = *(const v8s*)&Bz[(wn * 32 + nt * 16 + lrow) * 64 + aslot * 8];
#pragma unroll
        for (int mt = 0; mt < 4; ++mt)
#pragma unroll
          for (int nt = 0; nt < 2; ++nt)
            acc[z][mt][nt] = __builtin_amdgcn_mfma_f32_16x16x32_bf16(
                af[mt], bf[nt], acc[z][mt][nt], 0, 0, 0);
      }
    }
  }

  // Q and K: direct row-major stores
#pragma unroll
  for (int z = 0; z < 2; ++z) {
    unsigned short* Y = z ? Kw : Qw;
#pragma unroll
    for (int mt = 0; mt < 4; ++mt)
#pragma unroll
      for (int nt = 0; nt < 2; ++nt)
#pragma unroll
        for (int r = 0; r < 4; ++r) {
          int row = m0 + wm * 64 + mt * 16 + lq * 4 + r;
          int col = n0 + wn * 32 + nt * 16 + lrow;
          Y[(size_t)row * DM + col] = f2bf(acc[z][mt][nt][r]);
        }
  }

  // V: stage C-tile [128 t][64 d] swizzled in LDS, then b128 permuted panel
  __syncthreads();   // K-loop LDS reads done
#pragma unroll
  for (int mt = 0; mt < 4; ++mt)
#pragma unroll
    for (int nt = 0; nt < 2; ++nt)
#pragma unroll
      for (int r = 0; r < 4; ++r) {
        int trow = wm * 64 + mt * 16 + lq * 4 + r;     // 0..127 (token)
        int col  = wn * 32 + nt * 16 + lrow;           // 0..63  (d)
        int slot = (col >> 3) ^ (trow & 7);
        smem[trow * 64 + slot * 8 + (col & 7)] = f2bf(acc[2][mt][nt][r]);
      }
  __syncthreads();
  {
    const int d = tid & 63;
    const int quarter = tid >> 6;        // 32-key group
    const int bb = m0 >> 11;
    const int tblk = (m0 & 2047) >> 7;
    const int h = n0 >> 6;
    const int bh = bb * 16 + h;
    unsigned short* dst = Vtw + (((size_t)bh * 16 + tblk) * 64 + d) * 128;
    const int ch = d >> 3, e7 = d & 7;
#pragma unroll
    for (int jj = 0; jj < 4; ++jj) {
      unsigned short vals[8];
#pragma unroll
      for (int e = 0; e < 8; ++e) {
        int st = quarter * 32 + (e >> 2) * 16 + jj * 4 + (e & 3);  // source key
        vals[e] = smem[st * 64 + (ch ^ (st & 7)) * 8 + e7];
      }
      *(v8s*)(dst + (quarter * 4 + jj) * 8) = *(const v8s*)vals;
    }
  }
}

// ---------------------------------------------------------------------------
// Output projection (R5-proven): tile 64M x 128N, grid (64,8) = 512 = 2/CU.
// ---------------------------------------------------------------------------
__global__ __launch_bounds__(256) void oproj_gemm2(
    const unsigned short* __restrict__ AO,
    const unsigned short* __restrict__ Wob,
    float* __restrict__ Y)
{
  __shared__ unsigned short smem[12288];   // 24KB
  unsigned short* As = smem;               // [64][64]
  unsigned short* Bs = smem + 4096;        // [128][64]

  const int tid  = threadIdx.x;
  const int wv   = tid >> 6, l = tid & 63;
  const int lrow = l & 15, lq = l >> 4;
  const int wm = wv >> 1;
  const int wn = wv & 1;
  const int srow = l >> 3, sslot = l & 7;
  const int swz  = sslot ^ (srow & 7);
  const int m0 = blockIdx.x * 64, n0 = blockIdx.y * 128;

  v4f acc[2][4];
#pragma unroll
  for (int mt = 0; mt < 2; ++mt)
#pragma unroll
    for (int nt = 0; nt < 4; ++nt) acc[mt][nt] = (v4f){0.f, 0.f, 0.f, 0.f};

  const size_t aBase = (size_t)(m0 + wv * 16 + srow) * DM + swz * 8;
  const size_t bBase = (size_t)(n0 + wv * 32 + srow) * DM + swz * 8;

  for (int k0 = 0; k0 < DM; k0 += 64) {
    __syncthreads();
#pragma unroll
    for (int i = 0; i < 2; ++i)
      gload16(AO + aBase + (size_t)i * 8 * DM + k0, As + (wv * 16 + i * 8) * 64);
#pragma unroll
    for (int i = 0; i < 4; ++i)
      gload16(Wob + bBase + (size_t)i * 8 * DM + k0, Bs + (wv * 32 + i * 8) * 64);
    __syncthreads();
#pragma unroll
    for (int kc = 0; kc < 2; ++kc) {
      const int aslot = ((kc << 2) | lq) ^ (lrow & 7);
      v8s af[2], bf[4];
#pragma unroll
      for (int mt = 0; mt < 2; ++mt)
        af[mt] = *(const v8s*)&As[(wm * 32 + mt * 16 + lrow) * 64 + aslot * 8];
#pragma unroll
      for (int nt = 0; nt < 4; ++nt)
        bf[nt] = *(const v8s*)&Bs[(wn * 64 + nt * 16 + lrow) * 64 + aslot * 8];
#pragma unroll
      for (int mt = 0; mt < 2; ++mt)
#pragma unroll
        for (int nt = 0; nt < 4; ++nt)
          acc[mt][nt] = __builtin_amdgcn_mfma_f32_16x16x32_bf16(
              af[mt], bf[nt], acc[mt][nt], 0, 0, 0);
    }
  }
#pragma unroll
  for (int mt = 0; mt < 2; ++mt)
#pragma unroll
    for (int nt = 0; nt < 4; ++nt)
#pragma unroll
      for (int r = 0; r < 4; ++r) {
        int row = m0 + wm * 32 + mt * 16 + lq * 4 + r;
        int col = n0 + wn * 64 + nt * 16 + lrow;
        Y[(size_t)row * DM + col] = acc[mt][nt][r];
      }
}

// ---------------------------------------------------------------------------
// Flash attention v5: TRANSPOSED-S, register-resident P (no LDS round-trip).
// S^T = K Q^T: C-layout gives q=lane&15, key=quad*4+reg — exactly the
// B-operand layout for the PV K=32 mfma, given V's key-permuted panel.
// Fixed-base softmax (base cancels on normalization). LDS 32KB (Ks+Vts).
// ---------------------------------------------------------------------------
__global__ __launch_bounds__(256) void attn5(
    const unsigned short* __restrict__ Q,
    const unsigned short* __restrict__ K,
    const unsigned short* __restrict__ Vt,
    unsigned short* __restrict__ O)
{
  __shared__ unsigned short Ks[128 * 64];   // [key][d chunk swz]        16KB
  __shared__ unsigned short Vts[64 * 128];  // [d][key-permuted chunk]   16KB

  const int tid  = threadIdx.x;
  const int wave = tid >> 6;
  const int lane = tid & 63;
  const int lrow = lane & 15;
  const int lq   = lane >> 4;
  const int gid  = blockIdx.x;
  const int qt   = 31 - (gid >> 5);   // LPT: longest first
  const int bh   = gid & 31;
  const int b = bh >> 4, h = bh & 15;

  // Q fragment = B-operand of S^T mfma: n=q=lrow, k=d=lq*8+j
  const int qrow = qt * 64 + wave * 16 + lrow;
  const unsigned short* qp = Q + ((size_t)(b * T_SEQ + qrow)) * DM + h * 64;
  v8s qf0 = *(const v8s*)(qp + lq * 8);
  v8s qf1 = *(const v8s*)(qp + 32 + lq * 8);

  v4f oacc[4];
#pragma unroll
  for (int dt = 0; dt < 4; ++dt) oacc[dt] = (v4f){0.f, 0.f, 0.f, 0.f};
  float psum = 0.f;

  const int nkt = (qt >> 1) + 1;

  const int kchunk = (lane & 7) ^ ((lane >> 3) & 7);
  const unsigned short* kg =
      K + ((size_t)(b * T_SEQ) + wave * 8 + (lane >> 3)) * DM + h * 64 + kchunk * 8;
  unsigned short* kdst = Ks + (wave * 8) * 64;
  const int vd = wave * 4 + (lane >> 4);
  const int vslot = lane & 15;
  const int vchunk = (vslot & 8) | ((vslot & 7) ^ (vd & 7));
  const unsigned short* vg =
      Vt + ((size_t)bh * 1024 + vd) * 128 + vchunk * 8;
  unsigned short* vdst = Vts + (wave * 4) * 128;

  for (int kt = 0; kt < nkt; ++kt) {
    __syncthreads();
#pragma unroll
    for (int i = 0; i < 4; ++i)
      gload16(kg + ((size_t)kt * 128 + i * 32) * DM, kdst + i * 32 * 64);
#pragma unroll
    for (int i = 0; i < 4; ++i)
      gload16(vg + (size_t)kt * 8192 + i * 2048, vdst + i * 16 * 128);
    __syncthreads();

    // S^T = K Q^T : A = K frag (m=key, k=d), B = Q frag
    v4f s[8];
    const int slot0 = lq ^ (lrow & 7);
    const int slot1 = (4 + lq) ^ (lrow & 7);
#pragma unroll
    for (int nt = 0; nt < 8; ++nt) {
      v4f a = {0.f, 0.f, 0.f, 0.f};
      v8s k0 = *(const v8s*)&Ks[(nt * 16 + lrow) * 64 + slot0 * 8];
      a = __builtin_amdgcn_mfma_f32_16x16x32_bf16(k0, qf0, a, 0, 0, 0);
      v8s k1 = *(const v8s*)&Ks[(nt * 16 + lrow) * 64 + slot1 * 8];
      a = __builtin_amdgcn_mfma_f32_16x16x32_bf16(k1, qf1, a, 0, 0, 0);
      s[nt] = a;
    }

    // p = exp2(s*0.125*log2e - 16*log2e); causal mask on last tile only.
    // s[nt][r] holds S^T[key = kt*128 + nt*16 + lq*4 + r][q = lrow]
    const bool lastt = (kt == nkt - 1);
    if (lastt) {
#pragma unroll
      for (int nt = 0; nt < 8; ++nt)
#pragma unroll
        for (int r = 0; r < 4; ++r) {
          float p = exp2f(fmaf(s[nt][r], 0.18033688f, -23.0831206f));
          if (kt * 128 + nt * 16 + lq * 4 + r > qt * 64 + wave * 16 + lrow) p = 0.f;
          psum += p;
          s[nt][r] = p;
        }
    } else {
#pragma unroll
      for (int nt = 0; nt < 8; ++nt)
#pragma unroll
        for (int r = 0; r < 4; ++r) {
          float p = exp2f(fmaf(s[nt][r], 0.18033688f, -23.0831206f));
          psum += p;
          s[nt][r] = p;
        }
    }

    // P^T stays in registers: pack pairs of 16-key blocks into K=32 B-operands
    v8s pf[4];
#pragma unroll
    for (int kp = 0; kp < 4; ++kp) pf[kp] = pack8bf(s[2 * kp], s[2 * kp + 1]);

    // O^T += V^T P : A = V^T frag from permuted panel (key order matches pf)
#pragma unroll
    for (int dt = 0; dt < 4; ++dt)
#pragma unroll
      for (int kp = 0; kp < 4; ++kp) {
        int ch = kp * 4 + lq;
        int slot = (ch & 8) | ((ch & 7) ^ (lrow & 7));
        v8s vv = *(const v8s*)&Vts[(dt * 16 + lrow) * 128 + slot * 8];
        oacc[dt] = __builtin_amdgcn_mfma_f32_16x16x32_bf16(
            vv, pf[kp], oacc[dt], 0, 0, 0);
      }
  }

  // psum: reduce across the 4 quads sharing q = lrow
  psum += __shfl_xor(psum, 16);
  psum += __shfl_xor(psum, 32);
  const float rinv = 1.0f / psum;

  // O^T C-layout: q = lrow, d = dt*16 + lq*4 + r -> b64 packed stores
  const int token = qt * 64 + wave * 16 + lrow;
  unsigned short* op = O + ((size_t)(b * T_SEQ + token)) * DM + h * 64;
#pragma unroll
  for (int dt = 0; dt < 4; ++dt) {
    union { v4s s; unsigned int u[2]; } o;
    o.u[0] = (unsigned int)f2bf(oacc[dt][0] * rinv) |
             ((unsigned int)f2bf(oacc[dt][1] * rinv) << 16);
    o.u[1] = (unsigned int)f2bf(oacc[dt][2] * rinv) |
             ((unsigned int)f2bf(oacc[dt][3] * rinv) << 16);
    *(v4s*)(op + dt * 16 + lq * 4) = o.s;
  }
}

// ---------------------------------------------------------------------------
extern "C" void kernel_launch(void* const* d_in, const int* in_sizes, int n_in,
                              void* d_out, int out_size, void* d_ws, size_t ws_size,
                              hipStream_t stream) {
  const float* x  = (const float*)d_in[0];
  const float* Wq = (const float*)d_in[1];
  const float* Wk = (const float*)d_in[2];
  const float* Wv = (const float*)d_in[3];
  const float* Wo = (const float*)d_in[4];
  float* out = (float*)d_out;

  unsigned short* xb  = (unsigned short*)d_ws;
  unsigned short* wb  = xb + (size_t)MTOT * DM;
  unsigned short* Qw  = wb + (size_t)4 * DM * DM;
  unsigned short* Kw  = Qw + (size_t)MTOT * DM;
  unsigned short* Vtw = Kw + (size_t)MTOT * DM;
  unsigned short* AO  = xb;   // xb dead after qkv_fused2 -> reuse

  convert_all<<<8192, 256, 0, stream>>>(x, Wq, Wk, Wv, Wo, xb, wb);
  qkv_fused2<<<dim3(32, 16), 256, 0, stream>>>(xb, wb, Qw, Kw, Vtw);
  attn5<<<1024, 256, 0, stream>>>(Qw, Kw, Vtw, AO);
  oproj_gemm2<<<dim3(64, 8), 256, 0, stream>>>(AO, wb + (size_t)3 * DM * DM, out);
}

// Round 8
// 164.919 us; speedup vs baseline: 1.2221x; 1.0289x over previous
//
#include <hip/hip_runtime.h>
#include <hip/hip_bf16.h>

// Problem constants (B=2, T=2048, D=1024, H=16, hd=64)
#define T_SEQ 2048
#define DM    1024
#define MTOT  4096   // B*T

typedef short v8s __attribute__((ext_vector_type(8)));   // 8 x bf16 (4 VGPRs)
typedef short v4s __attribute__((ext_vector_type(4)));   // 4 x bf16 (2 VGPRs)
typedef float v4f __attribute__((ext_vector_type(4)));   // MFMA accumulator

// fp32 -> bf16 round-to-nearest-even (used on convert/GEMM paths)
__device__ __forceinline__ unsigned short f2bf(float f) {
  union { float f; unsigned int u; } x; x.f = f;
  return (unsigned short)((x.u + (((x.u >> 16) & 1u) + 0x7fffu)) >> 16);
}

// fast pack: two fp32 -> packed bf16x2 (round-half-up) via v_perm_b32
__device__ __forceinline__ unsigned int pk2(float a, float b) {
  unsigned int ua = __float_as_uint(a) + 0x8000u;
  unsigned int ub = __float_as_uint(b) + 0x8000u;
  return __builtin_amdgcn_perm(ub, ua, 0x07060302u);  // [ub_hi16, ua_hi16]
}

// pack two v4f (P^T C-layout regs) -> one v8s B-operand for K=32 PV mfma
__device__ __forceinline__ v8s pack8bf(v4f a, v4f b) {
  union { v8s s; unsigned int u[4]; } o;
  o.u[0] = pk2(a[0], a[1]);
  o.u[1] = pk2(a[2], a[3]);
  o.u[2] = pk2(b[0], b[1]);
  o.u[3] = pk2(b[2], b[3]);
  return o.s;
}

// raw v_exp_f32 (2^x); denormal output flushes to 0 which is what we want
__device__ __forceinline__ float fast_exp2(float x) {
#if __has_builtin(__builtin_amdgcn_exp2f)
  return __builtin_amdgcn_exp2f(x);
#else
  return exp2f(x);
#endif
}

// async global->LDS, 16B per lane: lane i lands at lds + i*16 (wave-uniform base).
__device__ __forceinline__ void gload16(const void* g, void* lds) {
  __builtin_amdgcn_global_load_lds(
      (const __attribute__((address_space(1))) unsigned int*)g,
      (__attribute__((address_space(3))) unsigned int*)lds, 16, 0, 0);
}

// ---------------------------------------------------------------------------
// Convert x + Wq/Wk/Wv/Wo to bf16 in workspace.
// ---------------------------------------------------------------------------
__global__ __launch_bounds__(256) void convert_all(
    const float* __restrict__ x,
    const float* __restrict__ Wq, const float* __restrict__ Wk,
    const float* __restrict__ Wv, const float* __restrict__ Wo,
    unsigned short* __restrict__ xb, unsigned short* __restrict__ wb)
{
  int i = blockIdx.x * 256 + threadIdx.x;   // float4 index, 2^21 total
  const float4* src;
  ushort4* dst;
  int idx;
  if (i < (1 << 20)) {
    src = (const float4*)x; dst = (ushort4*)xb; idx = i;
  } else {
    int j = i - (1 << 20);
    int wsel = j >> 18;
    idx = j & ((1 << 18) - 1);
    const float* s = (wsel == 0) ? Wq : (wsel == 1) ? Wk : (wsel == 2) ? Wv : Wo;
    src = (const float4*)s;
    dst = (ushort4*)(wb + (size_t)wsel * DM * DM);
  }
  float4 v = src[idx];
  ushort4 o = { f2bf(v.x), f2bf(v.y), f2bf(v.z), f2bf(v.w) };
  dst[idx] = o;
}

// ---------------------------------------------------------------------------
// FUSED QKV (R5-proven): tile 128M x 64N, grid (32,16) = 512 = 2/CU.
// LDS: As 16KB | Wq 8KB | Wk 8KB | Wv 8KB. XOR chunk swizzle.
// V epilogue: panel layout Vt[((bh*16+tblk)*64 + d)*128 + p] with PERMUTED
// key order matching the PV mfma's k-index mapping.
// ---------------------------------------------------------------------------
__global__ __launch_bounds__(256) void qkv_fused2(
    const unsigned short* __restrict__ xb,
    const unsigned short* __restrict__ wb,
    unsigned short* __restrict__ Qw, unsigned short* __restrict__ Kw,
    unsigned short* __restrict__ Vtw)
{
  __shared__ unsigned short smem[20480];   // 40KB
  unsigned short* As = smem;               // [128][64]

  const int tid  = threadIdx.x;
  const int wv   = tid >> 6, l = tid & 63;
  const int lrow = l & 15, lq = l >> 4;
  const int wm = wv >> 1;        // m-half (64 rows)
  const int wn = wv & 1;         // n-half (32 cols)
  const int srow = l >> 3, sslot = l & 7;
  const int swz  = sslot ^ (srow & 7);
  const int m0 = blockIdx.x * 128, n0 = blockIdx.y * 64;

  v4f acc[3][4][2];
#pragma unroll
  for (int z = 0; z < 3; ++z)
#pragma unroll
    for (int mt = 0; mt < 4; ++mt)
#pragma unroll
      for (int nt = 0; nt < 2; ++nt) acc[z][mt][nt] = (v4f){0.f, 0.f, 0.f, 0.f};

  const size_t aBase = (size_t)(m0 + wv * 32 + srow) * DM + swz * 8;
  const size_t bBase = (size_t)(n0 + wv * 16 + srow) * DM + swz * 8;

  for (int k0 = 0; k0 < DM; k0 += 64) {
    __syncthreads();
#pragma unroll
    for (int i = 0; i < 4; ++i)
      gload16(xb + aBase + (size_t)i * 8 * DM + k0, As + (wv * 32 + i * 8) * 64);
#pragma unroll
    for (int z = 0; z < 3; ++z)
#pragma unroll
      for (int i = 0; i < 2; ++i)
        gload16(wb + (size_t)z * DM * DM + bBase + (size_t)i * 8 * DM + k0,
                smem + 8192 + z * 4096 + (wv * 16 + i * 8) * 64);
    __syncthreads();
#pragma unroll
    for (int kc = 0; kc < 2; ++kc) {
      const int aslot = ((kc << 2) | lq) ^ (lrow & 7);
      v8s af[4];
#pragma unroll
      for (int mt = 0; mt < 4; ++mt)
        af[mt] = *(const v8s*)&As[(wm * 64 + mt * 16 + lrow) * 64 + aslot * 8];
#pragma unroll
      for (int z = 0; z < 3; ++z) {
        const unsigned short* Bz = smem + 8192 + z * 4096;
        v8s bf[2];
#pragma unroll
        for (int nt = 0; nt < 2; ++nt)
          bf[nt] = *(const v8s*)&Bz[(wn * 32 + nt * 16 + lrow) * 64 + aslot * 8];
#pragma unroll
        for (int mt = 0; mt < 4; ++mt)
#pragma unroll
          for (int nt = 0; nt < 2; ++nt)
            acc[z][mt][nt] = __builtin_amdgcn_mfma_f32_16x16x32_bf16(
                af[mt], bf[nt], acc[z][mt][nt], 0, 0, 0);
      }
    }
  }

  // Q and K: direct row-major stores
#pragma unroll
  for (int z = 0; z < 2; ++z) {
    unsigned short* Y = z ? Kw : Qw;
#pragma unroll
    for (int mt = 0; mt < 4; ++mt)
#pragma unroll
      for (int nt = 0; nt < 2; ++nt)
#pragma unroll
        for (int r = 0; r < 4; ++r) {
          int row = m0 + wm * 64 + mt * 16 + lq * 4 + r;
          int col = n0 + wn * 32 + nt * 16 + lrow;
          Y[(size_t)row * DM + col] = f2bf(acc[z][mt][nt][r]);
        }
  }

  // V: stage C-tile [128 t][64 d] swizzled in LDS, then b128 permuted panel
  __syncthreads();   // K-loop LDS reads done
#pragma unroll
  for (int mt = 0; mt < 4; ++mt)
#pragma unroll
    for (int nt = 0; nt < 2; ++nt)
#pragma unroll
      for (int r = 0; r < 4; ++r) {
        int trow = wm * 64 + mt * 16 + lq * 4 + r;     // 0..127 (token)
        int col  = wn * 32 + nt * 16 + lrow;           // 0..63  (d)
        int slot = (col >> 3) ^ (trow & 7);
        smem[trow * 64 + slot * 8 + (col & 7)] = f2bf(acc[2][mt][nt][r]);
      }
  __syncthreads();
  {
    const int d = tid & 63;
    const int quarter = tid >> 6;        // 32-key group
    const int bb = m0 >> 11;
    const int tblk = (m0 & 2047) >> 7;
    const int h = n0 >> 6;
    const int bh = bb * 16 + h;
    unsigned short* dst = Vtw + (((size_t)bh * 16 + tblk) * 64 + d) * 128;
    const int ch = d >> 3, e7 = d & 7;
#pragma unroll
    for (int jj = 0; jj < 4; ++jj) {
      unsigned short vals[8];
#pragma unroll
      for (int e = 0; e < 8; ++e) {
        int st = quarter * 32 + (e >> 2) * 16 + jj * 4 + (e & 3);  // source key
        vals[e] = smem[st * 64 + (ch ^ (st & 7)) * 8 + e7];
      }
      *(v8s*)(dst + (quarter * 4 + jj) * 8) = *(const v8s*)vals;
    }
  }
}

// ---------------------------------------------------------------------------
// Output projection (R5-proven): tile 64M x 128N, grid (64,8) = 512 = 2/CU.
// ---------------------------------------------------------------------------
__global__ __launch_bounds__(256) void oproj_gemm2(
    const unsigned short* __restrict__ AO,
    const unsigned short* __restrict__ Wob,
    float* __restrict__ Y)
{
  __shared__ unsigned short smem[12288];   // 24KB
  unsigned short* As = smem;               // [64][64]
  unsigned short* Bs = smem + 4096;        // [128][64]

  const int tid  = threadIdx.x;
  const int wv   = tid >> 6, l = tid & 63;
  const int lrow = l & 15, lq = l >> 4;
  const int wm = wv >> 1;
  const int wn = wv & 1;
  const int srow = l >> 3, sslot = l & 7;
  const int swz  = sslot ^ (srow & 7);
  const int m0 = blockIdx.x * 64, n0 = blockIdx.y * 128;

  v4f acc[2][4];
#pragma unroll
  for (int mt = 0; mt < 2; ++mt)
#pragma unroll
    for (int nt = 0; nt < 4; ++nt) acc[mt][nt] = (v4f){0.f, 0.f, 0.f, 0.f};

  const size_t aBase = (size_t)(m0 + wv * 16 + srow) * DM + swz * 8;
  const size_t bBase = (size_t)(n0 + wv * 32 + srow) * DM + swz * 8;

  for (int k0 = 0; k0 < DM; k0 += 64) {
    __syncthreads();
#pragma unroll
    for (int i = 0; i < 2; ++i)
      gload16(AO + aBase + (size_t)i * 8 * DM + k0, As + (wv * 16 + i * 8) * 64);
#pragma unroll
    for (int i = 0; i < 4; ++i)
      gload16(Wob + bBase + (size_t)i * 8 * DM + k0, Bs + (wv * 32 + i * 8) * 64);
    __syncthreads();
#pragma unroll
    for (int kc = 0; kc < 2; ++kc) {
      const int aslot = ((kc << 2) | lq) ^ (lrow & 7);
      v8s af[2], bf[4];
#pragma unroll
      for (int mt = 0; mt < 2; ++mt)
        af[mt] = *(const v8s*)&As[(wm * 32 + mt * 16 + lrow) * 64 + aslot * 8];
#pragma unroll
      for (int nt = 0; nt < 4; ++nt)
        bf[nt] = *(const v8s*)&Bs[(wn * 64 + nt * 16 + lrow) * 64 + aslot * 8];
#pragma unroll
      for (int mt = 0; mt < 2; ++mt)
#pragma unroll
        for (int nt = 0; nt < 4; ++nt)
          acc[mt][nt] = __builtin_amdgcn_mfma_f32_16x16x32_bf16(
              af[mt], bf[nt], acc[mt][nt], 0, 0, 0);
    }
  }
#pragma unroll
  for (int mt = 0; mt < 2; ++mt)
#pragma unroll
    for (int nt = 0; nt < 4; ++nt)
#pragma unroll
      for (int r = 0; r < 4; ++r) {
        int row = m0 + wm * 32 + mt * 16 + lq * 4 + r;
        int col = n0 + wn * 64 + nt * 16 + lrow;
        Y[(size_t)row * DM + col] = acc[mt][nt][r];
      }
}

// ---------------------------------------------------------------------------
// Flash attention v6: transposed-S, register-resident P, MFMA row-sums.
// S^T = K Q^T (C-layout: q=lane&15, key=quad*4+reg = PV B-operand layout).
// psum computed by mfma with A=ones: every lane gets its q's running key-sum
// in sacc[0] (all C rows identical; key permutation is sum-invariant).
// Fixed-base softmax: p = exp2(s*0.125*log2e - 16*log2e), base cancels.
// ---------------------------------------------------------------------------
__global__ __launch_bounds__(256) void attn6(
    const unsigned short* __restrict__ Q,
    const unsigned short* __restrict__ K,
    const unsigned short* __restrict__ Vt,
    unsigned short* __restrict__ O)
{
  __shared__ unsigned short Ks[128 * 64];   // [key][d chunk swz]        16KB
  __shared__ unsigned short Vts[64 * 128];  // [d][key-permuted chunk]   16KB

  const int tid  = threadIdx.x;
  const int wave = tid >> 6;
  const int lane = tid & 63;
  const int lrow = lane & 15;
  const int lq   = lane >> 4;
  const int gid  = blockIdx.x;
  const int qt   = 31 - (gid >> 5);   // LPT: longest first
  const int bh   = gid & 31;
  const int b = bh >> 4, h = bh & 15;

  // ones bf16 A-operand for the row-sum mfma
  union { v8s s; unsigned int u[4]; } ones;
  ones.u[0] = 0x3F803F80u; ones.u[1] = 0x3F803F80u;
  ones.u[2] = 0x3F803F80u; ones.u[3] = 0x3F803F80u;

  // Q fragment = B-operand of S^T mfma: n=q=lrow, k=d=lq*8+j
  const int qrow = qt * 64 + wave * 16 + lrow;
  const unsigned short* qp = Q + ((size_t)(b * T_SEQ + qrow)) * DM + h * 64;
  v8s qf0 = *(const v8s*)(qp + lq * 8);
  v8s qf1 = *(const v8s*)(qp + 32 + lq * 8);

  v4f oacc[4];
#pragma unroll
  for (int dt = 0; dt < 4; ++dt) oacc[dt] = (v4f){0.f, 0.f, 0.f, 0.f};
  v4f sacc = {0.f, 0.f, 0.f, 0.f};

  const int nkt = (qt >> 1) + 1;

  const int kchunk = (lane & 7) ^ ((lane >> 3) & 7);
  const unsigned short* kg =
      K + ((size_t)(b * T_SEQ) + wave * 8 + (lane >> 3)) * DM + h * 64 + kchunk * 8;
  unsigned short* kdst = Ks + (wave * 8) * 64;
  const int vd = wave * 4 + (lane >> 4);
  const int vslot = lane & 15;
  const int vchunk = (vslot & 8) | ((vslot & 7) ^ (vd & 7));
  const unsigned short* vg =
      Vt + ((size_t)bh * 1024 + vd) * 128 + vchunk * 8;
  unsigned short* vdst = Vts + (wave * 4) * 128;

  for (int kt = 0; kt < nkt; ++kt) {
    __syncthreads();
#pragma unroll
    for (int i = 0; i < 4; ++i)
      gload16(kg + ((size_t)kt * 128 + i * 32) * DM, kdst + i * 32 * 64);
#pragma unroll
    for (int i = 0; i < 4; ++i)
      gload16(vg + (size_t)kt * 8192 + i * 2048, vdst + i * 16 * 128);
    __syncthreads();

    // S^T = K Q^T : A = K frag (m=key, k=d), B = Q frag
    v4f s[8];
    const int slot0 = lq ^ (lrow & 7);
    const int slot1 = (4 + lq) ^ (lrow & 7);
#pragma unroll
    for (int nt = 0; nt < 8; ++nt) {
      v4f a = {0.f, 0.f, 0.f, 0.f};
      v8s k0 = *(const v8s*)&Ks[(nt * 16 + lrow) * 64 + slot0 * 8];
      a = __builtin_amdgcn_mfma_f32_16x16x32_bf16(k0, qf0, a, 0, 0, 0);
      v8s k1 = *(const v8s*)&Ks[(nt * 16 + lrow) * 64 + slot1 * 8];
      a = __builtin_amdgcn_mfma_f32_16x16x32_bf16(k1, qf1, a, 0, 0, 0);
      s[nt] = a;
    }

    // p = exp2(s*0.125*log2e - 16*log2e); causal mask on last tile only.
    // s[nt][r] holds S^T[key = kt*128 + nt*16 + lq*4 + r][q = lrow]
    const bool lastt = (kt == nkt - 1);
    if (lastt) {
#pragma unroll
      for (int nt = 0; nt < 8; ++nt)
#pragma unroll
        for (int r = 0; r < 4; ++r) {
          float p = fast_exp2(fmaf(s[nt][r], 0.18033688f, -23.0831206f));
          if (kt * 128 + nt * 16 + lq * 4 + r > qt * 64 + wave * 16 + lrow) p = 0.f;
          s[nt][r] = p;
        }
    } else {
#pragma unroll
      for (int nt = 0; nt < 8; ++nt)
#pragma unroll
        for (int r = 0; r < 4; ++r)
          s[nt][r] = fast_exp2(fmaf(s[nt][r], 0.18033688f, -23.0831206f));
    }

    // P^T stays in registers: pack pairs of 16-key blocks into K=32 B-operands
    v8s pf[4];
#pragma unroll
    for (int kp = 0; kp < 4; ++kp) pf[kp] = pack8bf(s[2 * kp], s[2 * kp + 1]);

    // O^T += V^T P ; row-sums += ones^T P (matrix pipe does the reduction)
#pragma unroll
    for (int kp = 0; kp < 4; ++kp) {
      sacc = __builtin_amdgcn_mfma_f32_16x16x32_bf16(ones.s, pf[kp], sacc, 0, 0, 0);
#pragma unroll
      for (int dt = 0; dt < 4; ++dt) {
        int ch = kp * 4 + lq;
        int slot = (ch & 8) | ((ch & 7) ^ (lrow & 7));
        v8s vv = *(const v8s*)&Vts[(dt * 16 + lrow) * 128 + slot * 8];
        oacc[dt] = __builtin_amdgcn_mfma_f32_16x16x32_bf16(
            vv, pf[kp], oacc[dt], 0, 0, 0);
      }
    }
  }

  // every lane already holds its q's key-sum (all sacc rows identical)
  const float rinv = 1.0f / sacc[0];

  // O^T C-layout: q = lrow, d = dt*16 + lq*4 + r -> b64 packed stores
  const int token = qt * 64 + wave * 16 + lrow;
  unsigned short* op = O + ((size_t)(b * T_SEQ + token)) * DM + h * 64;
#pragma unroll
  for (int dt = 0; dt < 4; ++dt) {
    union { v4s s; unsigned int u[2]; } o;
    o.u[0] = pk2(oacc[dt][0] * rinv, oacc[dt][1] * rinv);
    o.u[1] = pk2(oacc[dt][2] * rinv, oacc[dt][3] * rinv);
    *(v4s*)(op + dt * 16 + lq * 4) = o.s;
  }
}

// ---------------------------------------------------------------------------
extern "C" void kernel_launch(void* const* d_in, const int* in_sizes, int n_in,
                              void* d_out, int out_size, void* d_ws, size_t ws_size,
                              hipStream_t stream) {
  const float* x  = (const float*)d_in[0];
  const float* Wq = (const float*)d_in[1];
  const float* Wk = (const float*)d_in[2];
  const float* Wv = (const float*)d_in[3];
  const float* Wo = (const float*)d_in[4];
  float* out = (float*)d_out;

  unsigned short* xb  = (unsigned short*)d_ws;
  unsigned short* wb  = xb + (size_t)MTOT * DM;
  unsigned short* Qw  = wb + (size_t)4 * DM * DM;
  unsigned short* Kw  = Qw + (size_t)MTOT * DM;
  unsigned short* Vtw = Kw + (size_t)MTOT * DM;
  unsigned short* AO  = xb;   // xb dead after qkv_fused2 -> reuse

  convert_all<<<8192, 256, 0, stream>>>(x, Wq, Wk, Wv, Wo, xb, wb);
  qkv_fused2<<<dim3(32, 16), 256, 0, stream>>>(xb, wb, Qw, Kw, Vtw);
  attn6<<<1024, 256, 0, stream>>>(Qw, Kw, Vtw, AO);
  oproj_gemm2<<<dim3(64, 8), 256, 0, stream>>>(AO, wb + (size_t)3 * DM * DM, out);
}